// Round 10
// baseline (4973.928 us; speedup 1.0000x reference)
//
#include <hip/hip_runtime.h>

// Problem constants (fixed by setup_inputs)
#define BB 32
#define NN 64
#define TT 11
#define FF 4
#define KK 2
#define EE 4032      // N*(N-1)
#define NSTEP 10

typedef _Float16 f16x8 __attribute__((ext_vector_type(8)));
typedef float    f32x4v __attribute__((ext_vector_type(4)));

// ---- stage kernel LDS (dynamic): 38912 B -> 4 blocks/CU ----
#define U_STRIDE 264                    // u row: 256 f16 + 8 pad
#define OFF_U    0                      // u [64][264] f16 = 33792
#define OFF_VBH  33792                  // vbh [2 ri][256] f16 = 1024 (per-k rebuilt)
#define OFF_Y2   34816                  // y [64][4] f32 = 1024
#define OFF_WGT2 35840                  // wgt [2 k][128] f32 = 1024
#define OFF_AGG2 36864                  // agg [2 ri][256] f32 = 2048
#define SMEM2    38912

__device__ __forceinline__ float scrub(float v) {
    return fminf(fmaxf(v, -3.0e4f), 3.0e4f);   // inactive when correct (|x| <~ 600)
}

__device__ __forceinline__ float load_dt(const float* ts, const void* scp, int step) {
    float t0 = ts[step], t1 = ts[step + 1];
    int w = ((const int*)scp)[0];
    float scl;
    if (w > 0 && w < 1000000) scl = (float)w;            // int32 (live path)
    else {
        float f = __int_as_float(w);
        scl = (f > 0.5f && f < 1.0e6f) ? f : 10.0f;
    }
    return (t1 - t0) / scl;
}

// Edge-GEMM + aggregation for one RK4 stage. Block = (batch, 2 receivers).
// u-table (per-sender layer-1 partials, f16) in LDS; A-fragments via packed
// f16; B fragments from L2-resident pre-swizzled W2F with kc-level register
// prefetch (software pipeline over the ~250-cyc L2 latency).
__global__ __launch_bounds__(256, 4)
void stage_kernel(int stage, int step,
    const float* __restrict__ edges, const float* __restrict__ W1g,
    const float* __restrict__ b1g,   const _Float16* __restrict__ W2F,
    const float* __restrict__ b2g,   const float* __restrict__ ts,
    const void* __restrict__ scp,
    const float* __restrict__ xcur,  const float* __restrict__ kprev,
    float* __restrict__ aggg)
{
    extern __shared__ char smem[];
    _Float16* smU   = (_Float16*)(smem + OFF_U);
    _Float16* smVBH = (_Float16*)(smem + OFF_VBH);
    float*  smY   = (float*)(smem + OFF_Y2);
    float*  smWgt = (float*)(smem + OFF_WGT2);
    float*  smAgg = (float*)(smem + OFF_AGG2);

    const int tid = threadIdx.x;
    const int b   = blockIdx.x >> 5;
    const int rg  = blockIdx.x & 31;
    const int r0  = rg * 2;

    const float dt = load_dt(ts, scp, step);
    const float cc = (stage == 0) ? 0.0f : ((stage == 3) ? 1.0f : 0.5f);

    // ---- P0: y (all 64 nodes), edge weights, zero agg ----
    {
        int gi = (b * NN) * FF + tid;           // tid = n*4+f
        float y = xcur[gi];
        if (stage != 0) y += cc * dt * kprev[gi];
        smY[tid] = scrub(y);
    }
    {
        int k = tid >> 7, m = tid & 127;
        int ri = m >> 6, jj = m & 63, r = r0 + ri;
        float w = 0.0f;
        if (jj < 63) w = edges[((size_t)b * EE + r * 63 + jj) * KK + k];
        smWgt[tid] = w;
    }
    smAgg[tid] = 0.0f; smAgg[tid + 256] = 0.0f;

    const int lane = tid & 63;
    const int wave = tid >> 6;
    const int wm   = wave >> 1;   // receiver (row) half of M=128
    const int wn   = wave & 1;    // n-quarter selector (with ns)
    const int ln15 = lane & 15;
    const int lg   = lane >> 4;   // 0..3

    // sender index per mi: rows m = wm*64 + mi*16 + ln15
    const int rr_ = r0 + wm;      // this wave's receiver
    int svec[4];
    #pragma unroll
    for (int mi = 0; mi < 4; ++mi) {
        int mm = mi * 16 + ln15;
        int s = mm + (mm >= rr_ ? 1 : 0);
        svec[mi] = (s > 63) ? 63 : s;   // mm==63 is the pad row (wgt=0)
    }

    for (int k = 0; k < KK; ++k) {
        __syncthreads();          // P0 ready / prev-k readers of smU done
        // ---- u-build: u[s][h] = sum_f y_s[f] * W1send[k][f][h]  (f16) ----
        {
            int hg = tid & 31, sb = tid >> 5;
            const float* w1p = W1g + k * 2048 + hg * 8;
            f32x4v wA[4], wB[4];
            #pragma unroll
            for (int f = 0; f < 4; ++f) {
                wA[f] = *(const f32x4v*)(w1p + f * 256);
                wB[f] = *(const f32x4v*)(w1p + f * 256 + 4);
            }
            #pragma unroll
            for (int it = 0; it < 8; ++it) {
                int s = sb + it * 8;
                f32x4v yv = *(const f32x4v*)(smY + s * 4);
                f16x8 uv;
                #pragma unroll
                for (int e = 0; e < 4; ++e) {
                    float vA = yv[0]*wA[0][e] + yv[1]*wA[1][e] + yv[2]*wA[2][e] + yv[3]*wA[3][e];
                    float vB = yv[0]*wB[0][e] + yv[1]*wB[1][e] + yv[2]*wB[2][e] + yv[3]*wB[3][e];
                    uv[e]     = (_Float16)vA;
                    uv[e + 4] = (_Float16)vB;
                }
                *(f16x8*)(smU + s * U_STRIDE + hg * 8) = uv;
            }
        }
        // ---- vbh[ri][h] = f16( b1 + sum_f y_recv[f] * W1recv[k][f][h] ) ----
        for (int i = tid; i < 512; i += 256) {
            int ri = i >> 8, h = i & 255;
            float acc = b1g[k * 256 + h];
            #pragma unroll
            for (int f = 0; f < 4; ++f)
                acc += smY[(r0 + ri) * 4 + f] * W1g[k * 2048 + (4 + f) * 256 + h];
            smVBH[i] = (_Float16)acc;
        }
        __syncthreads();          // u + vbh ready

        // ---- GEMM: A-frags via packed-f16, B pipelined from L2 ----
        for (int ns = 0; ns < 2; ++ns) {
            f32x4v acc[4][4];
            #pragma unroll
            for (int mi = 0; mi < 4; ++mi)
                #pragma unroll
                for (int ni = 0; ni < 4; ++ni)
                    acc[mi][ni] = (f32x4v){0.f, 0.f, 0.f, 0.f};

            const _Float16* bbase = W2F
                + ((size_t)((k * 16 + ns * 8 + wn * 4) * 8)) * 512 + lane * 8;

            f16x8 bcur[4], bnxt[4];
            #pragma unroll
            for (int ni = 0; ni < 4; ++ni)
                bcur[ni] = *(const f16x8*)(bbase + (size_t)(ni * 8) * 512);

            #pragma unroll
            for (int kc = 0; kc < 8; ++kc) {
                // prefetch next kc's B while this kc's MFMAs run
                if (kc < 7) {
                    #pragma unroll
                    for (int ni = 0; ni < 4; ++ni)
                        bnxt[ni] = *(const f16x8*)(bbase + (size_t)(ni * 8 + kc + 1) * 512);
                }
                f16x8 vb8 = *(const f16x8*)(smVBH + wm * 256 + kc * 32 + lg * 8);
                #pragma unroll
                for (int mi = 0; mi < 4; ++mi) {
                    f16x8 uv = *(const f16x8*)(smU + svec[mi] * U_STRIDE + kc * 32 + lg * 8);
                    f16x8 z = {};
                    f16x8 af = __builtin_elementwise_max(uv + vb8, z);  // v_pk_add + v_pk_max
                    #pragma unroll
                    for (int ni = 0; ni < 4; ++ni)
                        acc[mi][ni] = __builtin_amdgcn_mfma_f32_16x16x32_f16(
                            af, bcur[ni], acc[mi][ni], 0, 0, 0);
                }
                #pragma unroll
                for (int ni = 0; ni < 4; ++ni) bcur[ni] = bnxt[ni];
            }

            // ---- epilogue: relu(+b2)*edge_w, reduce rows -> agg[wm][o] ----
            float bv[4], rsum[4];
            #pragma unroll
            for (int ni = 0; ni < 4; ++ni) {
                int o = (ns*8 + wn*4 + ni) * 16 + ln15;
                bv[ni] = b2g[k * 256 + o];
                rsum[ni] = 0.0f;
            }
            #pragma unroll
            for (int mi = 0; mi < 4; ++mi) {
                #pragma unroll
                for (int rr = 0; rr < 4; ++rr) {
                    // C/D: col = lane&15, row = (lane>>4)*4 + rr  [m89/m91]
                    float w = smWgt[k*128 + wm*64 + mi*16 + lg*4 + rr];
                    #pragma unroll
                    for (int ni = 0; ni < 4; ++ni)
                        rsum[ni] += fmaxf(acc[mi][ni][rr] + bv[ni], 0.0f) * w;
                }
            }
            #pragma unroll
            for (int ni = 0; ni < 4; ++ni) {
                rsum[ni] += __shfl_xor(rsum[ni], 16, 64);
                rsum[ni] += __shfl_xor(rsum[ni], 32, 64);
            }
            if (lane < 16) {
                #pragma unroll
                for (int ni = 0; ni < 4; ++ni) {
                    int o = (ns*8 + wn*4 + ni) * 16 + ln15;
                    smAgg[wm * 256 + o] += rsum[ni];   // unique (wave,o) writer
                }
            }
        }
    }
    __syncthreads();
    // ---- agg -> global (rows b*64 + r0 + ri) ----
    for (int i = tid; i < 512; i += 256)
        aggg[(size_t)(b * NN + r0 + (i >> 8)) * 256 + (i & 255)] = smAgg[i];
}

// Node MLP (f32-exact) + RK4 tail. Block = 8 rows; 256 blocks.
// col c = tid; 8 rows share each weight load; 16-wide load batches.
__global__ __launch_bounds__(256, 4)
void mlp_kernel(int stage, int step,
    const float* __restrict__ Wo1, const float* __restrict__ bo1,
    const float* __restrict__ Wo2, const float* __restrict__ bo2,
    const float* __restrict__ Wo3, const float* __restrict__ bo3,
    const float* __restrict__ ts,  const void* __restrict__ scp,
    const float* __restrict__ xcur, const float* __restrict__ kprev,
    const float* __restrict__ aggg,
    float* __restrict__ kout,
    const float* __restrict__ k1b, const float* __restrict__ k2b,
    const float* __restrict__ k3b,
    float* __restrict__ xnext, float* __restrict__ outp)
{
    __shared__ float smAug[8][264];    // 264 -> 16B-aligned rows for b128 reads
    __shared__ float smP1[8][256];
    __shared__ float smP2[8][256];

    const int tid  = threadIdx.x;
    const int row0 = blockIdx.x * 8;

    const float dt = load_dt(ts, scp, step);
    const float cc = (stage == 0) ? 0.0f : ((stage == 3) ? 1.0f : 0.5f);

    // ---- stage aug = [y(4) | agg(256)] per row ----
    for (int u = tid; u < 2080; u += 256) {
        int rr = u / 260, h = u - rr * 260;
        int row = row0 + rr;
        float v;
        if (h < 4) {
            int gi = row * 4 + h;
            v = xcur[gi];
            if (stage != 0) v += cc * dt * kprev[gi];
            v = scrub(v);
        } else {
            v = aggg[(size_t)row * 256 + (h - 4)];
        }
        smAug[rr][h] = v;
    }
    __syncthreads();

    // ---- L1: 260 -> 256, relu ----
    {
        int c = tid;
        float a[8];
        float b0 = bo1[c];
        #pragma unroll
        for (int rr = 0; rr < 8; ++rr) a[rr] = b0;
        #pragma unroll 1
        for (int hb = 0; hb < 256; hb += 16) {
            float w[16];
            #pragma unroll
            for (int j = 0; j < 16; ++j) w[j] = Wo1[(size_t)(hb + j) * 256 + c];
            #pragma unroll
            for (int j4 = 0; j4 < 4; ++j4) {
                f32x4v x[8];
                #pragma unroll
                for (int rr = 0; rr < 8; ++rr)
                    x[rr] = *(const f32x4v*)(&smAug[rr][hb + j4 * 4]);
                #pragma unroll
                for (int jj = 0; jj < 4; ++jj)
                    #pragma unroll
                    for (int rr = 0; rr < 8; ++rr)
                        a[rr] += x[rr][jj] * w[j4 * 4 + jj];
            }
        }
        #pragma unroll
        for (int j = 0; j < 4; ++j) {          // tail h = 256..259
            float wv = Wo1[(size_t)(256 + j) * 256 + c];
            #pragma unroll
            for (int rr = 0; rr < 8; ++rr)
                a[rr] += smAug[rr][256 + j] * wv;
        }
        #pragma unroll
        for (int rr = 0; rr < 8; ++rr)
            smP1[rr][c] = fmaxf(a[rr], 0.0f);
    }
    __syncthreads();
    // ---- L2: 256 -> 256, relu ----
    {
        int c = tid;
        float a[8];
        float b0 = bo2[c];
        #pragma unroll
        for (int rr = 0; rr < 8; ++rr) a[rr] = b0;
        #pragma unroll 1
        for (int hb = 0; hb < 256; hb += 16) {
            float w[16];
            #pragma unroll
            for (int j = 0; j < 16; ++j) w[j] = Wo2[(size_t)(hb + j) * 256 + c];
            #pragma unroll
            for (int j4 = 0; j4 < 4; ++j4) {
                f32x4v x[8];
                #pragma unroll
                for (int rr = 0; rr < 8; ++rr)
                    x[rr] = *(const f32x4v*)(&smP1[rr][hb + j4 * 4]);
                #pragma unroll
                for (int jj = 0; jj < 4; ++jj)
                    #pragma unroll
                    for (int rr = 0; rr < 8; ++rr)
                        a[rr] += x[rr][jj] * w[j4 * 4 + jj];
            }
        }
        #pragma unroll
        for (int rr = 0; rr < 8; ++rr)
            smP2[rr][c] = fmaxf(a[rr], 0.0f);
    }
    __syncthreads();
    // ---- L3 (256 -> 4) + residual + RK4 tail ----
    {
        int rr = tid >> 5, f = (tid >> 3) & 3, hs = tid & 7;
        float part = 0.0f;
        #pragma unroll
        for (int j = 0; j < 32; ++j) {
            int h = hs + j * 8;
            part += smP2[rr][h] * Wo3[h * 4 + f];
        }
        part += __shfl_xor(part, 4, 64);
        part += __shfl_xor(part, 2, 64);
        part += __shfl_xor(part, 1, 64);
        if (hs == 0) {
            int row = row0 + rr;
            int gi  = row * 4 + f;
            float y = xcur[gi];
            if (stage != 0) y += cc * dt * kprev[gi];
            y = scrub(y);
            float knew = scrub(y + bo3[f] + part);    // f(y) = y + p
            if (stage < 3) {
                kout[gi] = knew;
            } else {
                float xn = scrub(xcur[gi] + (dt * (1.0f / 6.0f)) *
                           (k1b[gi] + 2.0f * k2b[gi] + 2.0f * k3b[gi] + knew));
                xnext[gi] = xn;
                // out layout (B, N, NSTEP, F): row = b*64+n
                outp[(size_t)row * NSTEP * FF + step * FF + f] = xn;
            }
        }
    }
}

// Pre-swizzle W2 -> fragment-major W2F (verified round 7): chunk (k,ot,kc) is
// 1 KiB; lane l holds B[o = ot*16 + (l&15)][h = kc*32 + (l>>4)*8 + e]
__global__ void swizzle_w2(const float* __restrict__ W2, _Float16* __restrict__ W2F)
{
    int idx = blockIdx.x * 256 + threadIdx.x;       // 0 .. 131071
    int k   = idx >> 16;
    int rem = idx & 65535;
    int ch  = rem >> 9;
    int pos = rem & 511;
    int ot  = ch >> 3, kc = ch & 7;
    int l   = pos >> 3, e = pos & 7;
    int o   = ot * 16 + (l & 15);
    int h   = kc * 32 + (l >> 4) * 8 + e;
    W2F[idx] = (_Float16)W2[(size_t)(k * 256 + h) * 256 + o];
}

__global__ void init_x(const float* __restrict__ inp, float* __restrict__ x0)
{
    int i = blockIdx.x * 256 + threadIdx.x;   // i = (b*64+n)*4+f
    if (i < BB * NN * FF) {
        int f = i & 3, bn = i >> 2;
        x0[i] = scrub(inp[(size_t)(bn * TT) * FF + f]);   // inputs[b][n][0][f]
    }
}

static int find_input(const int* in_sizes, int n_in, int want, unsigned char* used, int dflt) {
    if (dflt >= 0 && dflt < n_in && in_sizes[dflt] == want && !used[dflt]) { used[dflt] = 1; return dflt; }
    for (int i = 0; i < n_in; ++i)
        if (!used[i] && in_sizes[i] == want) { used[i] = 1; return i; }
    return dflt;
}

extern "C" void kernel_launch(void* const* d_in, const int* in_sizes, int n_in,
                              void* d_out, int out_size, void* d_ws, size_t ws_size,
                              hipStream_t stream)
{
    unsigned char used[64] = {0};
    int iInp = find_input(in_sizes, n_in, BB*NN*TT*FF, used, 0);
    int iEdg = find_input(in_sizes, n_in, BB*EE*KK,    used, 1);
    (void)find_input(in_sizes, n_in, EE*NN, used, 2);              // rel_rec (unused)
    (void)find_input(in_sizes, n_in, EE*NN, used, 3);              // rel_send (unused)
    int iW1  = find_input(in_sizes, n_in, KK*8*256,  used, 4);
    int ib1  = find_input(in_sizes, n_in, KK*256,    used, 5);
    int iW2  = find_input(in_sizes, n_in, KK*256*256,used, 6);
    int ib2  = find_input(in_sizes, n_in, KK*256,    used, 7);
    int iWo1 = find_input(in_sizes, n_in, 260*256,   used, 8);
    int ibo1 = find_input(in_sizes, n_in, 256,       used, 9);
    int iWo2 = find_input(in_sizes, n_in, 256*256,   used, 10);
    int ibo2 = find_input(in_sizes, n_in, 256,       used, 11);
    int iWo3 = find_input(in_sizes, n_in, 256*4,     used, 12);
    int ibo3 = find_input(in_sizes, n_in, 4,         used, 13);
    int iTs  = find_input(in_sizes, n_in, TT,        used, 14);
    (void)find_input(in_sizes, n_in, 1, used, 15);                 // pred_steps
    int iSc  = find_input(in_sizes, n_in, 1,         used, 16);    // scale

    const float* inputs = (const float*)d_in[iInp];
    const float* edges  = (const float*)d_in[iEdg];
    const float* W1  = (const float*)d_in[iW1];
    const float* b1  = (const float*)d_in[ib1];
    const float* W2  = (const float*)d_in[iW2];
    const float* b2  = (const float*)d_in[ib2];
    const float* Wo1 = (const float*)d_in[iWo1];
    const float* bo1 = (const float*)d_in[ibo1];
    const float* Wo2 = (const float*)d_in[iWo2];
    const float* bo2 = (const float*)d_in[ibo2];
    const float* Wo3 = (const float*)d_in[iWo3];
    const float* bo3 = (const float*)d_in[ibo3];
    const float* ts  = (const float*)d_in[iTs];
    const void*  scp = d_in[iSc];

    char* ws = (char*)d_ws;
    _Float16* W2F = (_Float16*)ws;                     // 262144 B
    float* xA  = (float*)(ws + 262144);
    float* xB  = (float*)(ws + 262144 + 1 * 32768);
    float* k1  = (float*)(ws + 262144 + 2 * 32768);
    float* k2  = (float*)(ws + 262144 + 3 * 32768);
    float* k3  = (float*)(ws + 262144 + 4 * 32768);
    float* agg = (float*)(ws + 262144 + 5 * 32768);    // 2048*256*4 = 2 MiB

    float* outp = (float*)d_out;   // f32 output

    (void)hipFuncSetAttribute((const void*)stage_kernel,
        hipFuncAttributeMaxDynamicSharedMemorySize, SMEM2);

    swizzle_w2<<<dim3(512), dim3(256), 0, stream>>>(W2, W2F);
    init_x<<<dim3(32), dim3(256), 0, stream>>>(inputs, xA);

    float* xc = xA;
    float* xn = xB;
    for (int step = 0; step < NSTEP; ++step) {
        float* kprevs[4] = { xc, k1, k2, k3 };   // kprev per stage (xc unused at s0)
        float* kouts[4]  = { k1, k2, k3, k3 };   // kout per stage (s3 -> tail path)
        for (int s = 0; s < 4; ++s) {
            stage_kernel<<<dim3(1024), dim3(256), SMEM2, stream>>>(s, step,
                edges, W1, b1, W2F, b2, ts, scp, xc, kprevs[s], agg);
            mlp_kernel<<<dim3(256), dim3(256), 0, stream>>>(s, step,
                Wo1, bo1, Wo2, bo2, Wo3, bo3, ts, scp, xc, kprevs[s], agg,
                kouts[s], k1, k2, k3, xn, outp);
        }
        float* t = xc; xc = xn; xn = t;
    }
}

// Round 11
// 2689.001 us; speedup vs baseline: 1.8497x; 1.8497x over previous
//
#include <hip/hip_runtime.h>

// Problem constants (fixed by setup_inputs)
#define BB 32
#define NN 64
#define TT 11
#define FF 4
#define KK 2
#define EE 4032      // N*(N-1)
#define NSTEP 10

typedef _Float16 f16x8 __attribute__((ext_vector_type(8)));
typedef float    f32x4v __attribute__((ext_vector_type(4)));

// ---- stage kernel LDS (dynamic): 38912 B ----
#define U_STRIDE 264                    // u row: 256 f16 + 8 pad
#define OFF_U    0                      // u [64][264] f16 = 33792
#define OFF_VBH  33792                  // vbh [2 ri][256] f16 = 1024 (per-k rebuilt)
#define OFF_Y2   34816                  // y [64][4] f32 = 1024
#define OFF_WGT2 35840                  // wgt [2 k][128] f32 = 1024
#define OFF_AGG2 36864                  // agg [2 ri][256] f32 = 2048
#define SMEM2    38912

__device__ __forceinline__ float scrub(float v) {
    return fminf(fmaxf(v, -3.0e4f), 3.0e4f);   // inactive when correct (|x| <~ 600)
}

__device__ __forceinline__ float load_dt(const float* ts, const void* scp, int step) {
    float t0 = ts[step], t1 = ts[step + 1];
    int w = ((const int*)scp)[0];
    float scl;
    if (w > 0 && w < 1000000) scl = (float)w;            // int32 (live path)
    else {
        float f = __int_as_float(w);
        scl = (f > 0.5f && f < 1.0e6f) ? f : 10.0f;
    }
    return (t1 - t0) / scl;
}

// Edge-GEMM + aggregation for one RK4 stage. Block = (batch, 2 receivers).
// launch_bounds(256,3): 170-VGPR budget -> NO scratch spill (r8-r10 regression:
// (256,4) capped VGPR at 128-64acc and spilled 21-98 MB/dispatch to scratch).
__global__ __launch_bounds__(256, 3)
void stage_kernel(int stage, int step,
    const float* __restrict__ edges, const float* __restrict__ W1g,
    const float* __restrict__ b1g,   const _Float16* __restrict__ W2F,
    const float* __restrict__ b2g,   const float* __restrict__ ts,
    const void* __restrict__ scp,
    const float* __restrict__ xcur,  const float* __restrict__ kprev,
    float* __restrict__ aggg)
{
    extern __shared__ char smem[];
    _Float16* smU   = (_Float16*)(smem + OFF_U);
    _Float16* smVBH = (_Float16*)(smem + OFF_VBH);
    float*  smY   = (float*)(smem + OFF_Y2);
    float*  smWgt = (float*)(smem + OFF_WGT2);
    float*  smAgg = (float*)(smem + OFF_AGG2);

    const int tid = threadIdx.x;
    const int b   = blockIdx.x >> 5;
    const int rg  = blockIdx.x & 31;
    const int r0  = rg * 2;

    const float dt = load_dt(ts, scp, step);
    const float cc = (stage == 0) ? 0.0f : ((stage == 3) ? 1.0f : 0.5f);

    // ---- P0: y (all 64 nodes), edge weights, zero agg ----
    {
        int gi = (b * NN) * FF + tid;           // tid = n*4+f
        float y = xcur[gi];
        if (stage != 0) y += cc * dt * kprev[gi];
        smY[tid] = scrub(y);
    }
    {
        int k = tid >> 7, m = tid & 127;
        int ri = m >> 6, jj = m & 63, r = r0 + ri;
        float w = 0.0f;
        if (jj < 63) w = edges[((size_t)b * EE + r * 63 + jj) * KK + k];
        smWgt[tid] = w;
    }
    smAgg[tid] = 0.0f; smAgg[tid + 256] = 0.0f;

    const int lane = tid & 63;
    const int wave = tid >> 6;
    const int wm   = wave >> 1;   // receiver (row) half of M=128
    const int wn   = wave & 1;    // n-quarter selector (with ns)
    const int ln15 = lane & 15;
    const int lg   = lane >> 4;   // 0..3

    // sender index per mi: rows m = wm*64 + mi*16 + ln15
    const int rr_ = r0 + wm;      // this wave's receiver
    int svec[4];
    #pragma unroll
    for (int mi = 0; mi < 4; ++mi) {
        int mm = mi * 16 + ln15;
        int s = mm + (mm >= rr_ ? 1 : 0);
        svec[mi] = (s > 63) ? 63 : s;   // mm==63 is the pad row (wgt=0)
    }

    for (int k = 0; k < KK; ++k) {
        __syncthreads();          // P0 ready / prev-k readers of smU done
        // ---- u-build: u[s][h] = sum_f y_s[f] * W1send[k][f][h]  (f16) ----
        {
            int hg = tid & 31, sb = tid >> 5;
            const float* w1p = W1g + k * 2048 + hg * 8;
            f32x4v wA[4], wB[4];
            #pragma unroll
            for (int f = 0; f < 4; ++f) {
                wA[f] = *(const f32x4v*)(w1p + f * 256);
                wB[f] = *(const f32x4v*)(w1p + f * 256 + 4);
            }
            #pragma unroll
            for (int it = 0; it < 8; ++it) {
                int s = sb + it * 8;
                f32x4v yv = *(const f32x4v*)(smY + s * 4);
                f16x8 uv;
                #pragma unroll
                for (int e = 0; e < 4; ++e) {
                    float vA = yv[0]*wA[0][e] + yv[1]*wA[1][e] + yv[2]*wA[2][e] + yv[3]*wA[3][e];
                    float vB = yv[0]*wB[0][e] + yv[1]*wB[1][e] + yv[2]*wB[2][e] + yv[3]*wB[3][e];
                    uv[e]     = (_Float16)vA;
                    uv[e + 4] = (_Float16)vB;
                }
                *(f16x8*)(smU + s * U_STRIDE + hg * 8) = uv;
            }
        }
        // ---- vbh[ri][h] = f16( b1 + sum_f y_recv[f] * W1recv[k][f][h] ) ----
        for (int i = tid; i < 512; i += 256) {
            int ri = i >> 8, h = i & 255;
            float acc = b1g[k * 256 + h];
            #pragma unroll
            for (int f = 0; f < 4; ++f)
                acc += smY[(r0 + ri) * 4 + f] * W1g[k * 2048 + (4 + f) * 256 + h];
            smVBH[i] = (_Float16)acc;
        }
        __syncthreads();          // u + vbh ready

        // ---- GEMM: A-frags via packed-f16, B from L2 (compiler-scheduled) ----
        for (int ns = 0; ns < 2; ++ns) {
            f32x4v acc[4][4];
            #pragma unroll
            for (int mi = 0; mi < 4; ++mi)
                #pragma unroll
                for (int ni = 0; ni < 4; ++ni)
                    acc[mi][ni] = (f32x4v){0.f, 0.f, 0.f, 0.f};

            const _Float16* bbase = W2F
                + ((size_t)((k * 16 + ns * 8 + wn * 4) * 8)) * 512 + lane * 8;
            #pragma unroll
            for (int kc = 0; kc < 8; ++kc) {
                f16x8 bfr[4];
                #pragma unroll
                for (int ni = 0; ni < 4; ++ni)
                    bfr[ni] = *(const f16x8*)(bbase + (size_t)(ni * 8 + kc) * 512);
                f16x8 vb8 = *(const f16x8*)(smVBH + wm * 256 + kc * 32 + lg * 8);
                #pragma unroll
                for (int mi = 0; mi < 4; ++mi) {
                    f16x8 uv = *(const f16x8*)(smU + svec[mi] * U_STRIDE + kc * 32 + lg * 8);
                    f16x8 z = {};
                    f16x8 af = __builtin_elementwise_max(uv + vb8, z);  // v_pk_add + v_pk_max
                    #pragma unroll
                    for (int ni = 0; ni < 4; ++ni)
                        acc[mi][ni] = __builtin_amdgcn_mfma_f32_16x16x32_f16(
                            af, bfr[ni], acc[mi][ni], 0, 0, 0);
                }
            }

            // ---- epilogue: relu(+b2)*edge_w, reduce rows -> agg[wm][o] ----
            float bv[4], rsum[4];
            #pragma unroll
            for (int ni = 0; ni < 4; ++ni) {
                int o = (ns*8 + wn*4 + ni) * 16 + ln15;
                bv[ni] = b2g[k * 256 + o];
                rsum[ni] = 0.0f;
            }
            #pragma unroll
            for (int mi = 0; mi < 4; ++mi) {
                #pragma unroll
                for (int rr = 0; rr < 4; ++rr) {
                    // C/D: col = lane&15, row = (lane>>4)*4 + rr  [m89/m91]
                    float w = smWgt[k*128 + wm*64 + mi*16 + lg*4 + rr];
                    #pragma unroll
                    for (int ni = 0; ni < 4; ++ni)
                        rsum[ni] += fmaxf(acc[mi][ni][rr] + bv[ni], 0.0f) * w;
                }
            }
            #pragma unroll
            for (int ni = 0; ni < 4; ++ni) {
                rsum[ni] += __shfl_xor(rsum[ni], 16, 64);
                rsum[ni] += __shfl_xor(rsum[ni], 32, 64);
            }
            if (lane < 16) {
                #pragma unroll
                for (int ni = 0; ni < 4; ++ni) {
                    int o = (ns*8 + wn*4 + ni) * 16 + ln15;
                    smAgg[wm * 256 + o] += rsum[ni];   // unique (wave,o) writer
                }
            }
        }
    }
    __syncthreads();
    // ---- agg -> global (rows b*64 + r0 + ri) ----
    for (int i = tid; i < 512; i += 256)
        aggg[(size_t)(b * NN + r0 + (i >> 8)) * 256 + (i & 255)] = smAgg[i];
}

// Node MLP (f32-exact) + RK4 tail. Block = 4 rows; 512 blocks (>=2/CU).
// col c = tid; 4 rows share each weight load; 8-wide load batches.
__global__ __launch_bounds__(256, 4)
void mlp_kernel(int stage, int step,
    const float* __restrict__ Wo1, const float* __restrict__ bo1,
    const float* __restrict__ Wo2, const float* __restrict__ bo2,
    const float* __restrict__ Wo3, const float* __restrict__ bo3,
    const float* __restrict__ ts,  const void* __restrict__ scp,
    const float* __restrict__ xcur, const float* __restrict__ kprev,
    const float* __restrict__ aggg,
    float* __restrict__ kout,
    const float* __restrict__ k1b, const float* __restrict__ k2b,
    const float* __restrict__ k3b,
    float* __restrict__ xnext, float* __restrict__ outp)
{
    __shared__ float smAug[4][264];    // 264 -> 16B-aligned rows
    __shared__ float smP1[4][256];
    __shared__ float smP2[4][256];

    const int tid  = threadIdx.x;
    const int row0 = blockIdx.x * 4;

    const float dt = load_dt(ts, scp, step);
    const float cc = (stage == 0) ? 0.0f : ((stage == 3) ? 1.0f : 0.5f);

    // ---- stage aug = [y(4) | agg(256)] per row ----
    for (int u = tid; u < 1040; u += 256) {
        int rr = u / 260, h = u - rr * 260;
        int row = row0 + rr;
        float v;
        if (h < 4) {
            int gi = row * 4 + h;
            v = xcur[gi];
            if (stage != 0) v += cc * dt * kprev[gi];
            v = scrub(v);
        } else {
            v = aggg[(size_t)row * 256 + (h - 4)];
        }
        smAug[rr][h] = v;
    }
    __syncthreads();

    // ---- L1: 260 -> 256, relu ----
    {
        int c = tid;
        float a[4];
        float b0 = bo1[c];
        #pragma unroll
        for (int rr = 0; rr < 4; ++rr) a[rr] = b0;
        #pragma unroll 1
        for (int hb = 0; hb < 256; hb += 8) {
            float w[8];
            #pragma unroll
            for (int j = 0; j < 8; ++j) w[j] = Wo1[(size_t)(hb + j) * 256 + c];
            f32x4v xlo[4], xhi[4];
            #pragma unroll
            for (int rr = 0; rr < 4; ++rr) {
                xlo[rr] = *(const f32x4v*)(&smAug[rr][hb]);
                xhi[rr] = *(const f32x4v*)(&smAug[rr][hb + 4]);
            }
            #pragma unroll
            for (int jj = 0; jj < 4; ++jj)
                #pragma unroll
                for (int rr = 0; rr < 4; ++rr) {
                    a[rr] += xlo[rr][jj] * w[jj];
                    a[rr] += xhi[rr][jj] * w[4 + jj];
                }
        }
        #pragma unroll
        for (int j = 0; j < 4; ++j) {          // tail h = 256..259
            float wv = Wo1[(size_t)(256 + j) * 256 + c];
            #pragma unroll
            for (int rr = 0; rr < 4; ++rr)
                a[rr] += smAug[rr][256 + j] * wv;
        }
        #pragma unroll
        for (int rr = 0; rr < 4; ++rr)
            smP1[rr][c] = fmaxf(a[rr], 0.0f);
    }
    __syncthreads();
    // ---- L2: 256 -> 256, relu ----
    {
        int c = tid;
        float a[4];
        float b0 = bo2[c];
        #pragma unroll
        for (int rr = 0; rr < 4; ++rr) a[rr] = b0;
        #pragma unroll 1
        for (int hb = 0; hb < 256; hb += 8) {
            float w[8];
            #pragma unroll
            for (int j = 0; j < 8; ++j) w[j] = Wo2[(size_t)(hb + j) * 256 + c];
            f32x4v xlo[4], xhi[4];
            #pragma unroll
            for (int rr = 0; rr < 4; ++rr) {
                xlo[rr] = *(const f32x4v*)(&smP1[rr][hb]);
                xhi[rr] = *(const f32x4v*)(&smP1[rr][hb + 4]);
            }
            #pragma unroll
            for (int jj = 0; jj < 4; ++jj)
                #pragma unroll
                for (int rr = 0; rr < 4; ++rr) {
                    a[rr] += xlo[rr][jj] * w[jj];
                    a[rr] += xhi[rr][jj] * w[4 + jj];
                }
        }
        #pragma unroll
        for (int rr = 0; rr < 4; ++rr)
            smP2[rr][c] = fmaxf(a[rr], 0.0f);
    }
    __syncthreads();
    // ---- L3 (256 -> 4) + residual + RK4 tail ----
    {
        int rr = tid >> 6, f = (tid >> 4) & 3, hs = tid & 15;
        float part = 0.0f;
        #pragma unroll
        for (int j = 0; j < 16; ++j) {
            int h = hs + j * 16;
            part += smP2[rr][h] * Wo3[h * 4 + f];
        }
        part += __shfl_xor(part, 8, 64);
        part += __shfl_xor(part, 4, 64);
        part += __shfl_xor(part, 2, 64);
        part += __shfl_xor(part, 1, 64);
        if (hs == 0) {
            int row = row0 + rr;
            int gi  = row * 4 + f;
            float y = xcur[gi];
            if (stage != 0) y += cc * dt * kprev[gi];
            y = scrub(y);
            float knew = scrub(y + bo3[f] + part);    // f(y) = y + p
            if (stage < 3) {
                kout[gi] = knew;
            } else {
                float xn = scrub(xcur[gi] + (dt * (1.0f / 6.0f)) *
                           (k1b[gi] + 2.0f * k2b[gi] + 2.0f * k3b[gi] + knew));
                xnext[gi] = xn;
                // out layout (B, N, NSTEP, F): row = b*64+n
                outp[(size_t)row * NSTEP * FF + step * FF + f] = xn;
            }
        }
    }
}

// Pre-swizzle W2 -> fragment-major W2F (verified round 7): chunk (k,ot,kc) is
// 1 KiB; lane l holds B[o = ot*16 + (l&15)][h = kc*32 + (l>>4)*8 + e]
__global__ void swizzle_w2(const float* __restrict__ W2, _Float16* __restrict__ W2F)
{
    int idx = blockIdx.x * 256 + threadIdx.x;       // 0 .. 131071
    int k   = idx >> 16;
    int rem = idx & 65535;
    int ch  = rem >> 9;
    int pos = rem & 511;
    int ot  = ch >> 3, kc = ch & 7;
    int l   = pos >> 3, e = pos & 7;
    int o   = ot * 16 + (l & 15);
    int h   = kc * 32 + (l >> 4) * 8 + e;
    W2F[idx] = (_Float16)W2[(size_t)(k * 256 + h) * 256 + o];
}

__global__ void init_x(const float* __restrict__ inp, float* __restrict__ x0)
{
    int i = blockIdx.x * 256 + threadIdx.x;   // i = (b*64+n)*4+f
    if (i < BB * NN * FF) {
        int f = i & 3, bn = i >> 2;
        x0[i] = scrub(inp[(size_t)(bn * TT) * FF + f]);   // inputs[b][n][0][f]
    }
}

static int find_input(const int* in_sizes, int n_in, int want, unsigned char* used, int dflt) {
    if (dflt >= 0 && dflt < n_in && in_sizes[dflt] == want && !used[dflt]) { used[dflt] = 1; return dflt; }
    for (int i = 0; i < n_in; ++i)
        if (!used[i] && in_sizes[i] == want) { used[i] = 1; return i; }
    return dflt;
}

extern "C" void kernel_launch(void* const* d_in, const int* in_sizes, int n_in,
                              void* d_out, int out_size, void* d_ws, size_t ws_size,
                              hipStream_t stream)
{
    unsigned char used[64] = {0};
    int iInp = find_input(in_sizes, n_in, BB*NN*TT*FF, used, 0);
    int iEdg = find_input(in_sizes, n_in, BB*EE*KK,    used, 1);
    (void)find_input(in_sizes, n_in, EE*NN, used, 2);              // rel_rec (unused)
    (void)find_input(in_sizes, n_in, EE*NN, used, 3);              // rel_send (unused)
    int iW1  = find_input(in_sizes, n_in, KK*8*256,  used, 4);
    int ib1  = find_input(in_sizes, n_in, KK*256,    used, 5);
    int iW2  = find_input(in_sizes, n_in, KK*256*256,used, 6);
    int ib2  = find_input(in_sizes, n_in, KK*256,    used, 7);
    int iWo1 = find_input(in_sizes, n_in, 260*256,   used, 8);
    int ibo1 = find_input(in_sizes, n_in, 256,       used, 9);
    int iWo2 = find_input(in_sizes, n_in, 256*256,   used, 10);
    int ibo2 = find_input(in_sizes, n_in, 256,       used, 11);
    int iWo3 = find_input(in_sizes, n_in, 256*4,     used, 12);
    int ibo3 = find_input(in_sizes, n_in, 4,         used, 13);
    int iTs  = find_input(in_sizes, n_in, TT,        used, 14);
    (void)find_input(in_sizes, n_in, 1, used, 15);                 // pred_steps
    int iSc  = find_input(in_sizes, n_in, 1,         used, 16);    // scale

    const float* inputs = (const float*)d_in[iInp];
    const float* edges  = (const float*)d_in[iEdg];
    const float* W1  = (const float*)d_in[iW1];
    const float* b1  = (const float*)d_in[ib1];
    const float* W2  = (const float*)d_in[iW2];
    const float* b2  = (const float*)d_in[ib2];
    const float* Wo1 = (const float*)d_in[iWo1];
    const float* bo1 = (const float*)d_in[ibo1];
    const float* Wo2 = (const float*)d_in[iWo2];
    const float* bo2 = (const float*)d_in[ibo2];
    const float* Wo3 = (const float*)d_in[iWo3];
    const float* bo3 = (const float*)d_in[ibo3];
    const float* ts  = (const float*)d_in[iTs];
    const void*  scp = d_in[iSc];

    char* ws = (char*)d_ws;
    _Float16* W2F = (_Float16*)ws;                     // 262144 B
    float* xA  = (float*)(ws + 262144);
    float* xB  = (float*)(ws + 262144 + 1 * 32768);
    float* k1  = (float*)(ws + 262144 + 2 * 32768);
    float* k2  = (float*)(ws + 262144 + 3 * 32768);
    float* k3  = (float*)(ws + 262144 + 4 * 32768);
    float* agg = (float*)(ws + 262144 + 5 * 32768);    // 2048*256*4 = 2 MiB

    float* outp = (float*)d_out;   // f32 output

    (void)hipFuncSetAttribute((const void*)stage_kernel,
        hipFuncAttributeMaxDynamicSharedMemorySize, SMEM2);

    swizzle_w2<<<dim3(512), dim3(256), 0, stream>>>(W2, W2F);
    init_x<<<dim3(32), dim3(256), 0, stream>>>(inputs, xA);

    float* xc = xA;
    float* xn = xB;
    for (int step = 0; step < NSTEP; ++step) {
        float* kprevs[4] = { xc, k1, k2, k3 };   // kprev per stage (xc unused at s0)
        float* kouts[4]  = { k1, k2, k3, k3 };   // kout per stage (s3 -> tail path)
        for (int s = 0; s < 4; ++s) {
            stage_kernel<<<dim3(1024), dim3(256), SMEM2, stream>>>(s, step,
                edges, W1, b1, W2F, b2, ts, scp, xc, kprevs[s], agg);
            mlp_kernel<<<dim3(512), dim3(256), 0, stream>>>(s, step,
                Wo1, bo1, Wo2, bo2, Wo3, bo3, ts, scp, xc, kprevs[s], agg,
                kouts[s], k1, k2, k3, xn, outp);
        }
        float* t = xc; xc = xn; xn = t;
    }
}

// Round 12
// 2644.103 us; speedup vs baseline: 1.8811x; 1.0170x over previous
//
#include <hip/hip_runtime.h>

// Problem constants (fixed by setup_inputs)
#define BB 32
#define NN 64
#define TT 11
#define FF 4
#define KK 2
#define EE 4032      // N*(N-1)
#define NSTEP 10

typedef _Float16 f16x8 __attribute__((ext_vector_type(8)));
typedef float    f32x4v __attribute__((ext_vector_type(4)));

// ---- stage kernel LDS (dynamic): 36864 B ----
#define U_STRIDE 264                    // u row: 256 f16 + 8 pad (b128 reads bank-balanced)
#define OFF_U    0                      // u [64][264] f16 = 33792
#define OFF_VBH  33792                  // vbh [2 ri][256] f16 = 1024 (per-k rebuilt)
#define OFF_Y2   34816                  // y [64][4] f32 = 1024
#define OFF_WGT2 35840                  // wgt [2 k][128] f32 = 1024
#define SMEM2    36864

__device__ __forceinline__ float scrub(float v) {
    return fminf(fmaxf(v, -3.0e4f), 3.0e4f);   // inactive when correct (|x| <~ 600)
}

__device__ __forceinline__ float load_dt(const float* ts, const void* scp, int step) {
    float t0 = ts[step], t1 = ts[step + 1];
    int w = ((const int*)scp)[0];
    float scl;
    if (w > 0 && w < 1000000) scl = (float)w;            // int32 (live path)
    else {
        float f = __int_as_float(w);
        scl = (f > 0.5f && f < 1.0e6f) ? f : 10.0f;
    }
    return (t1 - t0) / scl;
}

// Edge-GEMM + aggregation for one RK4 stage. Block = (batch, 2 receivers).
// Wave layout (r12): each wave covers ALL 128 rows (8 mi-tiles, acc[8][4]) and
// a DISTINCT 64-col quarter (wn = wave) per k -> B-fragment L2 traffic halved
// (no inter-wave duplication) and af cached per kc (reused by 4 MFMAs).
// launch_bounds(256,2): 256-VGPR cap, no spill (acc 128 + af 32 + bfr 16 + misc).
__global__ __launch_bounds__(256, 2)
void stage_kernel(int stage, int step,
    const float* __restrict__ edges, const float* __restrict__ W1g,
    const float* __restrict__ b1g,   const _Float16* __restrict__ W2F,
    const float* __restrict__ b2g,   const float* __restrict__ ts,
    const void* __restrict__ scp,
    const float* __restrict__ xcur,  const float* __restrict__ kprev,
    float* __restrict__ aggg)
{
    extern __shared__ char smem[];
    _Float16* smU   = (_Float16*)(smem + OFF_U);
    _Float16* smVBH = (_Float16*)(smem + OFF_VBH);
    float*  smY   = (float*)(smem + OFF_Y2);
    float*  smWgt = (float*)(smem + OFF_WGT2);

    const int tid = threadIdx.x;
    const int b   = blockIdx.x >> 5;
    const int rg  = blockIdx.x & 31;
    const int r0  = rg * 2;

    const float dt = load_dt(ts, scp, step);
    const float cc = (stage == 0) ? 0.0f : ((stage == 3) ? 1.0f : 0.5f);

    // ---- P0: y (all 64 nodes), edge weights ----
    {
        int gi = (b * NN) * FF + tid;           // tid = n*4+f
        float y = xcur[gi];
        if (stage != 0) y += cc * dt * kprev[gi];
        smY[tid] = scrub(y);
    }
    {
        int k = tid >> 7, m = tid & 127;        // m = rl*64 + jj
        int rl = m >> 6, jj = m & 63, r = r0 + rl;
        float w = 0.0f;
        if (jj < 63) w = edges[((size_t)b * EE + r * 63 + jj) * KK + k];
        smWgt[tid] = w;
    }

    const int lane = tid & 63;
    const int wn   = tid >> 6;    // wave = col-quarter owner (0..3)
    const int ln15 = lane & 15;
    const int lg   = lane >> 4;   // 0..3

    // sender index per mi (8 tiles cover all 128 rows): row m = mi*16 + ln15
    int svec[8];
    #pragma unroll
    for (int mi = 0; mi < 8; ++mi) {
        int mm = mi * 16 + ln15;
        int rl = mm >> 6, jj = mm & 63;
        int s = jj + (jj >= (r0 + rl) ? 1 : 0);
        svec[mi] = (s > 63) ? 63 : s;   // jj==63 is the pad slot (wgt=0)
    }

    float rsumT[2][4];            // [receiver][ni], accumulated across k
    #pragma unroll
    for (int rc = 0; rc < 2; ++rc)
        #pragma unroll
        for (int ni = 0; ni < 4; ++ni) rsumT[rc][ni] = 0.0f;

    for (int k = 0; k < KK; ++k) {
        __syncthreads();          // P0 ready / prev-k readers of smU done
        // ---- u-build: u[s][h] = sum_f y_s[f] * W1send[k][f][h]  (f16) ----
        {
            int hg = tid & 31, sb = tid >> 5;
            const float* w1p = W1g + k * 2048 + hg * 8;
            f32x4v wA[4], wB[4];
            #pragma unroll
            for (int f = 0; f < 4; ++f) {
                wA[f] = *(const f32x4v*)(w1p + f * 256);
                wB[f] = *(const f32x4v*)(w1p + f * 256 + 4);
            }
            #pragma unroll
            for (int it = 0; it < 8; ++it) {
                int s = sb + it * 8;
                f32x4v yv = *(const f32x4v*)(smY + s * 4);
                f16x8 uv;
                #pragma unroll
                for (int e = 0; e < 4; ++e) {
                    float vA = yv[0]*wA[0][e] + yv[1]*wA[1][e] + yv[2]*wA[2][e] + yv[3]*wA[3][e];
                    float vB = yv[0]*wB[0][e] + yv[1]*wB[1][e] + yv[2]*wB[2][e] + yv[3]*wB[3][e];
                    uv[e]     = (_Float16)vA;
                    uv[e + 4] = (_Float16)vB;
                }
                *(f16x8*)(smU + s * U_STRIDE + hg * 8) = uv;
            }
        }
        // ---- vbh[rl][h] = f16( b1 + sum_f y_recv[f] * W1recv[k][f][h] ) ----
        for (int i = tid; i < 512; i += 256) {
            int rl = i >> 8, h = i & 255;
            float acch = b1g[k * 256 + h];
            #pragma unroll
            for (int f = 0; f < 4; ++f)
                acch += smY[(r0 + rl) * 4 + f] * W1g[k * 2048 + (4 + f) * 256 + h];
            smVBH[i] = (_Float16)acch;
        }
        __syncthreads();          // u + vbh ready

        // ---- GEMM: kc-outer, af[8] cached, 4 ni-MFMAs per af ----
        f32x4v acc[8][4];
        #pragma unroll
        for (int mi = 0; mi < 8; ++mi)
            #pragma unroll
            for (int ni = 0; ni < 4; ++ni)
                acc[mi][ni] = (f32x4v){0.f, 0.f, 0.f, 0.f};

        const _Float16* bbase = W2F
            + ((size_t)((k * 16 + wn * 4) * 8)) * 512 + lane * 8;
        #pragma unroll
        for (int kc = 0; kc < 8; ++kc) {
            f16x8 bfr[4];
            #pragma unroll
            for (int ni = 0; ni < 4; ++ni)
                bfr[ni] = *(const f16x8*)(bbase + (size_t)(ni * 8 + kc) * 512);
            f16x8 vbA = *(const f16x8*)(smVBH + 0 * 256 + kc * 32 + lg * 8);
            f16x8 vbB = *(const f16x8*)(smVBH + 1 * 256 + kc * 32 + lg * 8);
            f16x8 af[8];
            f16x8 z = {};
            #pragma unroll
            for (int mi = 0; mi < 8; ++mi) {
                f16x8 uv = *(const f16x8*)(smU + svec[mi] * U_STRIDE + kc * 32 + lg * 8);
                af[mi] = __builtin_elementwise_max(uv + (mi < 4 ? vbA : vbB), z);
            }
            #pragma unroll
            for (int mi = 0; mi < 8; ++mi)
                #pragma unroll
                for (int ni = 0; ni < 4; ++ni)
                    acc[mi][ni] = __builtin_amdgcn_mfma_f32_16x16x32_f16(
                        af[mi], bfr[ni], acc[mi][ni], 0, 0, 0);
        }

        // ---- epilogue (per k): relu(+b2)*edge_w, accumulate rsumT ----
        float bv[4];
        #pragma unroll
        for (int ni = 0; ni < 4; ++ni)
            bv[ni] = b2g[k * 256 + wn * 64 + ni * 16 + ln15];
        #pragma unroll
        for (int mi = 0; mi < 8; ++mi) {
            int rc = mi >> 2;
            #pragma unroll
            for (int rr = 0; rr < 4; ++rr) {
                // C/D: col = lane&15, row = (lane>>4)*4 + rr  [m89/m91]
                float w = smWgt[k*128 + mi*16 + lg*4 + rr];
                #pragma unroll
                for (int ni = 0; ni < 4; ++ni)
                    rsumT[rc][ni] += fmaxf(acc[mi][ni][rr] + bv[ni], 0.0f) * w;
            }
        }
    }

    // ---- cross-lane reduce + direct global agg write (unique (row,o) writer) ----
    #pragma unroll
    for (int rc = 0; rc < 2; ++rc)
        #pragma unroll
        for (int ni = 0; ni < 4; ++ni) {
            rsumT[rc][ni] += __shfl_xor(rsumT[rc][ni], 16, 64);
            rsumT[rc][ni] += __shfl_xor(rsumT[rc][ni], 32, 64);
        }
    if (lane < 16) {
        #pragma unroll
        for (int rc = 0; rc < 2; ++rc)
            #pragma unroll
            for (int ni = 0; ni < 4; ++ni) {
                int o = wn * 64 + ni * 16 + ln15;
                aggg[(size_t)(b * NN + r0 + rc) * 256 + o] = rsumT[rc][ni];
            }
    }
}

// Node MLP (f32-exact) + RK4 tail. Block = 4 rows; 512 blocks (>=2/CU).
__global__ __launch_bounds__(256, 4)
void mlp_kernel(int stage, int step,
    const float* __restrict__ Wo1, const float* __restrict__ bo1,
    const float* __restrict__ Wo2, const float* __restrict__ bo2,
    const float* __restrict__ Wo3, const float* __restrict__ bo3,
    const float* __restrict__ ts,  const void* __restrict__ scp,
    const float* __restrict__ xcur, const float* __restrict__ kprev,
    const float* __restrict__ aggg,
    float* __restrict__ kout,
    const float* __restrict__ k1b, const float* __restrict__ k2b,
    const float* __restrict__ k3b,
    float* __restrict__ xnext, float* __restrict__ outp)
{
    __shared__ float smAug[4][264];    // 264 -> 16B-aligned rows
    __shared__ float smP1[4][256];
    __shared__ float smP2[4][256];

    const int tid  = threadIdx.x;
    const int row0 = blockIdx.x * 4;

    const float dt = load_dt(ts, scp, step);
    const float cc = (stage == 0) ? 0.0f : ((stage == 3) ? 1.0f : 0.5f);

    // ---- stage aug = [y(4) | agg(256)] per row ----
    for (int u = tid; u < 1040; u += 256) {
        int rr = u / 260, h = u - rr * 260;
        int row = row0 + rr;
        float v;
        if (h < 4) {
            int gi = row * 4 + h;
            v = xcur[gi];
            if (stage != 0) v += cc * dt * kprev[gi];
            v = scrub(v);
        } else {
            v = aggg[(size_t)row * 256 + (h - 4)];
        }
        smAug[rr][h] = v;
    }
    __syncthreads();

    // ---- L1: 260 -> 256, relu ----
    {
        int c = tid;
        float a[4];
        float b0 = bo1[c];
        #pragma unroll
        for (int rr = 0; rr < 4; ++rr) a[rr] = b0;
        #pragma unroll 1
        for (int hb = 0; hb < 256; hb += 8) {
            float w[8];
            #pragma unroll
            for (int j = 0; j < 8; ++j) w[j] = Wo1[(size_t)(hb + j) * 256 + c];
            f32x4v xlo[4], xhi[4];
            #pragma unroll
            for (int rr = 0; rr < 4; ++rr) {
                xlo[rr] = *(const f32x4v*)(&smAug[rr][hb]);
                xhi[rr] = *(const f32x4v*)(&smAug[rr][hb + 4]);
            }
            #pragma unroll
            for (int jj = 0; jj < 4; ++jj)
                #pragma unroll
                for (int rr = 0; rr < 4; ++rr) {
                    a[rr] += xlo[rr][jj] * w[jj];
                    a[rr] += xhi[rr][jj] * w[4 + jj];
                }
        }
        #pragma unroll
        for (int j = 0; j < 4; ++j) {          // tail h = 256..259
            float wv = Wo1[(size_t)(256 + j) * 256 + c];
            #pragma unroll
            for (int rr = 0; rr < 4; ++rr)
                a[rr] += smAug[rr][256 + j] * wv;
        }
        #pragma unroll
        for (int rr = 0; rr < 4; ++rr)
            smP1[rr][c] = fmaxf(a[rr], 0.0f);
    }
    __syncthreads();
    // ---- L2: 256 -> 256, relu ----
    {
        int c = tid;
        float a[4];
        float b0 = bo2[c];
        #pragma unroll
        for (int rr = 0; rr < 4; ++rr) a[rr] = b0;
        #pragma unroll 1
        for (int hb = 0; hb < 256; hb += 8) {
            float w[8];
            #pragma unroll
            for (int j = 0; j < 8; ++j) w[j] = Wo2[(size_t)(hb + j) * 256 + c];
            f32x4v xlo[4], xhi[4];
            #pragma unroll
            for (int rr = 0; rr < 4; ++rr) {
                xlo[rr] = *(const f32x4v*)(&smP1[rr][hb]);
                xhi[rr] = *(const f32x4v*)(&smP1[rr][hb + 4]);
            }
            #pragma unroll
            for (int jj = 0; jj < 4; ++jj)
                #pragma unroll
                for (int rr = 0; rr < 4; ++rr) {
                    a[rr] += xlo[rr][jj] * w[jj];
                    a[rr] += xhi[rr][jj] * w[4 + jj];
                }
        }
        #pragma unroll
        for (int rr = 0; rr < 4; ++rr)
            smP2[rr][c] = fmaxf(a[rr], 0.0f);
    }
    __syncthreads();
    // ---- L3 (256 -> 4) + residual + RK4 tail ----
    {
        int rr = tid >> 6, f = (tid >> 4) & 3, hs = tid & 15;
        float part = 0.0f;
        #pragma unroll
        for (int j = 0; j < 16; ++j) {
            int h = hs + j * 16;
            part += smP2[rr][h] * Wo3[h * 4 + f];
        }
        part += __shfl_xor(part, 8, 64);
        part += __shfl_xor(part, 4, 64);
        part += __shfl_xor(part, 2, 64);
        part += __shfl_xor(part, 1, 64);
        if (hs == 0) {
            int row = row0 + rr;
            int gi  = row * 4 + f;
            float y = xcur[gi];
            if (stage != 0) y += cc * dt * kprev[gi];
            y = scrub(y);
            float knew = scrub(y + bo3[f] + part);    // f(y) = y + p
            if (stage < 3) {
                kout[gi] = knew;
            } else {
                float xn = scrub(xcur[gi] + (dt * (1.0f / 6.0f)) *
                           (k1b[gi] + 2.0f * k2b[gi] + 2.0f * k3b[gi] + knew));
                xnext[gi] = xn;
                // out layout (B, N, NSTEP, F): row = b*64+n
                outp[(size_t)row * NSTEP * FF + step * FF + f] = xn;
            }
        }
    }
}

// Pre-swizzle W2 -> fragment-major W2F (verified round 7): chunk (k,ot,kc) is
// 1 KiB; lane l holds B[o = ot*16 + (l&15)][h = kc*32 + (l>>4)*8 + e]
__global__ void swizzle_w2(const float* __restrict__ W2, _Float16* __restrict__ W2F)
{
    int idx = blockIdx.x * 256 + threadIdx.x;       // 0 .. 131071
    int k   = idx >> 16;
    int rem = idx & 65535;
    int ch  = rem >> 9;
    int pos = rem & 511;
    int ot  = ch >> 3, kc = ch & 7;
    int l   = pos >> 3, e = pos & 7;
    int o   = ot * 16 + (l & 15);
    int h   = kc * 32 + (l >> 4) * 8 + e;
    W2F[idx] = (_Float16)W2[(size_t)(k * 256 + h) * 256 + o];
}

__global__ void init_x(const float* __restrict__ inp, float* __restrict__ x0)
{
    int i = blockIdx.x * 256 + threadIdx.x;   // i = (b*64+n)*4+f
    if (i < BB * NN * FF) {
        int f = i & 3, bn = i >> 2;
        x0[i] = scrub(inp[(size_t)(bn * TT) * FF + f]);   // inputs[b][n][0][f]
    }
}

static int find_input(const int* in_sizes, int n_in, int want, unsigned char* used, int dflt) {
    if (dflt >= 0 && dflt < n_in && in_sizes[dflt] == want && !used[dflt]) { used[dflt] = 1; return dflt; }
    for (int i = 0; i < n_in; ++i)
        if (!used[i] && in_sizes[i] == want) { used[i] = 1; return i; }
    return dflt;
}

extern "C" void kernel_launch(void* const* d_in, const int* in_sizes, int n_in,
                              void* d_out, int out_size, void* d_ws, size_t ws_size,
                              hipStream_t stream)
{
    unsigned char used[64] = {0};
    int iInp = find_input(in_sizes, n_in, BB*NN*TT*FF, used, 0);
    int iEdg = find_input(in_sizes, n_in, BB*EE*KK,    used, 1);
    (void)find_input(in_sizes, n_in, EE*NN, used, 2);              // rel_rec (unused)
    (void)find_input(in_sizes, n_in, EE*NN, used, 3);              // rel_send (unused)
    int iW1  = find_input(in_sizes, n_in, KK*8*256,  used, 4);
    int ib1  = find_input(in_sizes, n_in, KK*256,    used, 5);
    int iW2  = find_input(in_sizes, n_in, KK*256*256,used, 6);
    int ib2  = find_input(in_sizes, n_in, KK*256,    used, 7);
    int iWo1 = find_input(in_sizes, n_in, 260*256,   used, 8);
    int ibo1 = find_input(in_sizes, n_in, 256,       used, 9);
    int iWo2 = find_input(in_sizes, n_in, 256*256,   used, 10);
    int ibo2 = find_input(in_sizes, n_in, 256,       used, 11);
    int iWo3 = find_input(in_sizes, n_in, 256*4,     used, 12);
    int ibo3 = find_input(in_sizes, n_in, 4,         used, 13);
    int iTs  = find_input(in_sizes, n_in, TT,        used, 14);
    (void)find_input(in_sizes, n_in, 1, used, 15);                 // pred_steps
    int iSc  = find_input(in_sizes, n_in, 1,         used, 16);    // scale

    const float* inputs = (const float*)d_in[iInp];
    const float* edges  = (const float*)d_in[iEdg];
    const float* W1  = (const float*)d_in[iW1];
    const float* b1  = (const float*)d_in[ib1];
    const float* W2  = (const float*)d_in[iW2];
    const float* b2  = (const float*)d_in[ib2];
    const float* Wo1 = (const float*)d_in[iWo1];
    const float* bo1 = (const float*)d_in[ibo1];
    const float* Wo2 = (const float*)d_in[iWo2];
    const float* bo2 = (const float*)d_in[ibo2];
    const float* Wo3 = (const float*)d_in[iWo3];
    const float* bo3 = (const float*)d_in[ibo3];
    const float* ts  = (const float*)d_in[iTs];
    const void*  scp = d_in[iSc];

    char* ws = (char*)d_ws;
    _Float16* W2F = (_Float16*)ws;                     // 262144 B
    float* xA  = (float*)(ws + 262144);
    float* xB  = (float*)(ws + 262144 + 1 * 32768);
    float* k1  = (float*)(ws + 262144 + 2 * 32768);
    float* k2  = (float*)(ws + 262144 + 3 * 32768);
    float* k3  = (float*)(ws + 262144 + 4 * 32768);
    float* agg = (float*)(ws + 262144 + 5 * 32768);    // 2048*256*4 = 2 MiB

    float* outp = (float*)d_out;   // f32 output

    (void)hipFuncSetAttribute((const void*)stage_kernel,
        hipFuncAttributeMaxDynamicSharedMemorySize, SMEM2);

    swizzle_w2<<<dim3(512), dim3(256), 0, stream>>>(W2, W2F);
    init_x<<<dim3(32), dim3(256), 0, stream>>>(inputs, xA);

    float* xc = xA;
    float* xn = xB;
    for (int step = 0; step < NSTEP; ++step) {
        float* kprevs[4] = { xc, k1, k2, k3 };   // kprev per stage (xc unused at s0)
        float* kouts[4]  = { k1, k2, k3, k3 };   // kout per stage (s3 -> tail path)
        for (int s = 0; s < 4; ++s) {
            stage_kernel<<<dim3(1024), dim3(256), SMEM2, stream>>>(s, step,
                edges, W1, b1, W2F, b2, ts, scp, xc, kprevs[s], agg);
            mlp_kernel<<<dim3(512), dim3(256), 0, stream>>>(s, step,
                Wo1, bo1, Wo2, bo2, Wo3, bo3, ts, scp, xc, kprevs[s], agg,
                kouts[s], k1, k2, k3, xn, outp);
        }
        float* t = xc; xc = xn; xn = t;
    }
}